// Round 22
// baseline (75.446 us; speedup 1.0000x reference)
//
#include <hip/hip_runtime.h>

typedef unsigned int uint32;
typedef unsigned short ushort16;
typedef __attribute__((ext_vector_type(16))) float f32x16;
typedef __attribute__((ext_vector_type(8)))  short short8;

#define THREADS 256
#define FR 2        // A-fragments per wave -> 64 queries/wave, 1 b-read / 2 MFMA
#define QB 256      // queries per block (4 waves x 64)
#define CH 8        // 32-point tiles per LDS chunk (8 KB/buf, 16 KB dbuf)
#define JS 16       // j-slices -> 64x16x2 = 2048 blocks = 8/CU
#define RB 128      // reduce stage-1 blocks

__device__ inline ushort16 bf16rn(float x) {
    uint32 u = __float_as_uint(x);
    u += 0x7FFFu + ((u >> 16) & 1u);
    return (ushort16)(u >> 16);
}
__device__ inline float bf2f(ushort16 h) { return __uint_as_float(((uint32)h) << 16); }

// K=16 slot map v2 (R21-proven, C = 0):
//   slots 4cc..4cc+3: Q:[ah,ah,am,am]  S:[bh,bm,bh,bm] (b=-2c)  -> -2 a.b
//   slots 12,13: Q:[a2h,a2m] S:[1,1]  -> |a|^2
//   slots 14,15: Q:[1,1]     S:[b2h,b2m] -> |b|^2
// D = |a|^2 + |b|^2 - 2 a.b with C=0 (no pc registers).
// Pad scan cols: ss[14]=1e30 -> never win row-min. Padded query rows are
// simply never written out (qi < nq guard).
__device__ inline void prep_q(const float* __restrict__ P, int np, int i,
                              short8* __restrict__ Qf)
{
    ushort16 qs[16];
#pragma unroll
    for (int s = 0; s < 16; ++s) qs[s] = 0;
    if (i < np) {
        float c[3] = {P[3*i], P[3*i+1], P[3*i+2]};
        float w = fmaf(c[0], c[0], fmaf(c[1], c[1], c[2]*c[2]));
#pragma unroll
        for (int cc = 0; cc < 3; ++cc) {
            ushort16 h = bf16rn(c[cc]);
            ushort16 md = bf16rn(c[cc] - bf2f(h));
            const int b = 4*cc;
            qs[b]=h; qs[b+1]=h; qs[b+2]=md; qs[b+3]=md;
        }
        ushort16 wh = bf16rn(w);
        qs[12]=wh; qs[13]=bf16rn(w - bf2f(wh));
        qs[14]=0x3F80; qs[15]=0x3F80;
    }
    const int row = i & 31, grp = i >> 5;
#pragma unroll
    for (int h = 0; h < 2; ++h) {
        short8 qv;
#pragma unroll
        for (int e = 0; e < 8; ++e) qv[e] = (short)qs[8*h+e];
        Qf[(size_t)grp*64 + h*32 + row] = qv;
    }
}

__device__ inline void prep_s(const float* __restrict__ P, int np, int i,
                              short8* __restrict__ Sf)
{
    ushort16 ss[16];
#pragma unroll
    for (int s = 0; s < 16; ++s) ss[s] = 0;
    if (i < np) {
        float c[3] = {P[3*i], P[3*i+1], P[3*i+2]};
        float w = fmaf(c[0], c[0], fmaf(c[1], c[1], c[2]*c[2]));
#pragma unroll
        for (int cc = 0; cc < 3; ++cc) {
            float bv = -2.f * c[cc];
            ushort16 bh = bf16rn(bv);
            ushort16 bm = bf16rn(bv - bf2f(bh));
            const int b = 4*cc;
            ss[b]=bh; ss[b+1]=bm; ss[b+2]=bh; ss[b+3]=bm;
        }
        ss[12]=0x3F80; ss[13]=0x3F80;
        ushort16 wh = bf16rn(w);
        ss[14]=wh; ss[15]=bf16rn(w - bf2f(wh));
    } else {
        ss[14] = bf16rn(1e30f);   // sentinel: padded scan point never wins
    }
    const int row = i & 31, grp = i >> 5;
#pragma unroll
    for (int h = 0; h < 2; ++h) {
        short8 sv;
#pragma unroll
        for (int e = 0; e < 8; ++e) sv[e] = (short)ss[8*h+e];
        Sf[(size_t)grp*64 + h*32 + row] = sv;
    }
}

__global__ __launch_bounds__(THREADS) void cd_prep(
    const float* __restrict__ A, int n, int padN,
    const float* __restrict__ B, int m, int padM,
    short8* QfA, short8* SfA, short8* QfB, short8* SfB,
    uint32* __restrict__ bits)
{
    const int i = blockIdx.x * THREADS + threadIdx.x;
    if (i < n + m) bits[i] = 0x7F800000u;  // +inf
    if (i < padN) { prep_q(A, n, i, QfA); prep_s(A, n, i, SfA); }
    if (i < padM) { prep_q(B, m, i, QfB); prep_s(B, m, i, SfB); }
}

__device__ inline float dppmin(float v, int ctrl) {
    float s;
    switch (ctrl) {
        case 0xB1:  s = __int_as_float(__builtin_amdgcn_mov_dpp(__float_as_int(v), 0xB1,  0xf, 0xf, false)); break; // xor1
        case 0x4E:  s = __int_as_float(__builtin_amdgcn_mov_dpp(__float_as_int(v), 0x4E,  0xf, 0xf, false)); break; // xor2
        case 0x141: s = __int_as_float(__builtin_amdgcn_mov_dpp(__float_as_int(v), 0x141, 0xf, 0xf, false)); break; // half_mirror
        default:    s = __int_as_float(__builtin_amdgcn_mov_dpp(__float_as_int(v), 0x140, 0xf, 0xf, false)); break; // row_mirror
    }
    return fminf(v, s);
}

// TWO-PASS (blockIdx.z) 32x32x16 MFMA chamfer, FR=2-serial: each B-tile read
// feeds TWO MFMAs (av0, av1) -> DS-read pipe halves (was the co-limit at
// 24.6k cyc/CU). Zero-C via K-slot-v2 (no pc regs); per-tile VALU stays the
// minimal 8 min3/MFMA. cA/cB pair gives MFMA ILP at 32 result regs. Inner
// unroll bounded (R20: full unroll hoists all ds_reads -> spill). No forced
// launch_bounds minimum (R19/R20: forcing pins VGPR and spills).
// C layout (m74/m101): col=lane&31, row=(reg&3)+8*(reg>>2)+4*(lane>>5).
// Row-mins: DPP butterfly + xor16; atomicMin on float bits (>=0, exact).
__global__ __launch_bounds__(THREADS) void cd_mfma(
    const short8* __restrict__ QfA, const short8* __restrict__ SfA, int padN, int n,
    const short8* __restrict__ QfB, const short8* __restrict__ SfB, int padM, int m,
    uint32* __restrict__ bits)
{
    __shared__ short8 sb[2][CH*64];

    const short8* Qf; const short8* Sf; uint32* outb;
    int nq, padQ, padS;
    if (blockIdx.z == 0) { Qf=QfA; nq=n; padQ=padN; Sf=SfB; padS=padM; outb=bits;   }
    else                 { Qf=QfB; nq=m; padQ=padM; Sf=SfA; padS=padN; outb=bits+n; }

    if ((int)(blockIdx.x * QB) >= padQ) return;
    const int ntiles = padS >> 5;
    const int tps = ((ntiles + JS*CH - 1) / (JS*CH)) * CH;
    const int t0 = blockIdx.y * tps;
    const int t1 = min(t0 + tps, ntiles);
    if (t0 >= t1) return;

    const int tid = threadIdx.x, lane = tid & 63, wid = tid >> 6;
    const int qbase = blockIdx.x * QB + wid * (FR * 32);

    short8 av0 = Qf[(size_t)(qbase >> 5) * 64 + lane];
    short8 av1 = Qf[(size_t)((qbase >> 5) + 1) * 64 + lane];

    float rmin[FR][16];
#pragma unroll
    for (int f = 0; f < FR; ++f)
#pragma unroll
        for (int r = 0; r < 16; ++r) rmin[f][r] = 1e30f;

    const f32x16 zero = {0.f,0.f,0.f,0.f,0.f,0.f,0.f,0.f,
                         0.f,0.f,0.f,0.f,0.f,0.f,0.f,0.f};
    const int nch = (t1 - t0 + CH - 1) / CH;

    // prologue: stage chunk 0 (CH*64 = 512 short8, 2 per thread)
    {
        const int elems = min(CH, t1 - t0) * 64;
        if (tid       < elems) sb[0][tid      ] = Sf[(size_t)t0*64 + tid      ];
        if (tid + 256 < elems) sb[0][tid + 256] = Sf[(size_t)t0*64 + tid + 256];
    }
    __syncthreads();

    int cur = 0;
    for (int ch = 0; ch < nch; ++ch) {
        const int tb = t0 + ch*CH;
        const int cnt = min(CH, t1 - tb);

        // issue next chunk's global loads EARLY (hide under MFMA phase)
        short8 st0, st1;
        bool sv0=false, sv1=false;
        if (ch + 1 < nch) {
            const int nb = tb + CH;
            const int nel = min(CH, t1 - nb) * 64;
            const size_t gb = (size_t)nb * 64;
            if (tid       < nel) { st0 = Sf[gb + tid      ]; sv0 = true; }
            if (tid + 256 < nel) { st1 = Sf[gb + tid + 256]; sv1 = true; }
        }

#pragma unroll 2
        for (int t = 0; t < cnt; ++t) {
            const short8 b = sb[cur][t*64 + lane];
            const f32x16 cA = __builtin_amdgcn_mfma_f32_32x32x16_bf16(av0, b, zero, 0, 0, 0);
            const f32x16 cB = __builtin_amdgcn_mfma_f32_32x32x16_bf16(av1, b, zero, 0, 0, 0);
#pragma unroll
            for (int r = 0; r < 16; ++r) {
                rmin[0][r] = fminf(rmin[0][r], cA[r]);
                rmin[1][r] = fminf(rmin[1][r], cB[r]);
            }
        }

        if (ch + 1 < nch) {  // write-late into the other buffer
            if (sv0) sb[cur^1][tid      ] = st0;
            if (sv1) sb[cur^1][tid + 256] = st1;
        }
        __syncthreads();
        cur ^= 1;
    }

    // row-min over the 32 columns: DPP butterfly + one xor16 shuffle
#pragma unroll
    for (int f = 0; f < FR; ++f)
#pragma unroll
        for (int r = 0; r < 16; ++r) {
            float v = rmin[f][r];
            v = dppmin(v, 0xB1);
            v = dppmin(v, 0x4E);
            v = dppmin(v, 0x141);
            v = dppmin(v, 0x140);
            v = fminf(v, __shfl_xor(v, 16, 64));
            rmin[f][r] = v;
        }

    if ((lane & 31) == 0) {
        const int h4 = (lane >> 5) * 4;
#pragma unroll
        for (int f = 0; f < FR; ++f) {
            const int rb = qbase + f*32 + h4;
#pragma unroll
            for (int r = 0; r < 16; ++r) {
                const int qi = rb + (r & 3) + 8 * (r >> 2);
                if (qi < nq)
                    atomicMin(&outb[qi], __float_as_uint(fmaxf(rmin[f][r], 0.f)));
            }
        }
    }
}

__global__ __launch_bounds__(THREADS) void cd_reduce1(
    const uint32* __restrict__ bits, int count, double* __restrict__ partials)
{
    double s = 0.0;
    for (int i = blockIdx.x * THREADS + threadIdx.x; i < count; i += gridDim.x * THREADS)
        s += (double)sqrtf(__uint_as_float(bits[i]));
#pragma unroll
    for (int off = 32; off; off >>= 1) s += __shfl_down(s, off, 64);
    __shared__ double sw[4];
    const int lane = threadIdx.x & 63, wid = threadIdx.x >> 6;
    if (lane == 0) sw[wid] = s;
    __syncthreads();
    if (threadIdx.x == 0) partials[blockIdx.x] = sw[0] + sw[1] + sw[2] + sw[3];
}

__global__ __launch_bounds__(THREADS) void cd_reduce2(
    const double* __restrict__ partials, int nb, int total, float* __restrict__ out)
{
    double s = 0.0;
    for (int i = threadIdx.x; i < nb; i += THREADS) s += partials[i];
#pragma unroll
    for (int off = 32; off; off >>= 1) s += __shfl_down(s, off, 64);
    __shared__ double sw[4];
    const int lane = threadIdx.x & 63, wid = threadIdx.x >> 6;
    if (lane == 0) sw[wid] = s;
    __syncthreads();
    if (threadIdx.x == 0)
        out[0] = (float)((sw[0] + sw[1] + sw[2] + sw[3]) / (double)total);
}

extern "C" void kernel_launch(void* const* d_in, const int* in_sizes, int n_in,
                              void* d_out, int out_size, void* d_ws, size_t ws_size,
                              hipStream_t stream) {
    const float* a = (const float*)d_in[0];
    const float* b = (const float*)d_in[1];
    const int n = in_sizes[0] / 3;
    const int m = in_sizes[1] / 3;
    const int total = n + m;
    float* out = (float*)d_out;

    const int padN = (n + QB - 1) / QB * QB;
    const int padM = (m + QB - 1) / QB * QB;

    // ws: QfA | SfA | QfB | SfB | bits | partials
    char* wp = (char*)d_ws;
    short8* QfA = (short8*)wp;   wp += (size_t)padN * 32;
    short8* SfA = (short8*)wp;   wp += (size_t)padN * 32;
    short8* QfB = (short8*)wp;   wp += (size_t)padM * 32;
    short8* SfB = (short8*)wp;   wp += (size_t)padM * 32;
    uint32* bits = (uint32*)wp;  wp += (size_t)total * 4;
    wp = (char*)(((size_t)wp + 255) & ~(size_t)255);
    double* partials = (double*)wp;

    const int prepElems = max(max(padN, padM), total);
    cd_prep<<<(prepElems + THREADS - 1) / THREADS, THREADS, 0, stream>>>(
        a, n, padN, b, m, padM, QfA, SfA, QfB, SfB, bits);

    const int gx = max(padN, padM) / QB;
    dim3 grid(gx, JS, 2);
    cd_mfma<<<grid, THREADS, 0, stream>>>(QfA, SfA, padN, n,
                                          QfB, SfB, padM, m, bits);

    cd_reduce1<<<RB, THREADS, 0, stream>>>(bits, total, partials);
    cd_reduce2<<<1, THREADS, 0, stream>>>(partials, RB, total, out);
}

// Round 23
// 43.228 us; speedup vs baseline: 1.7453x; 1.7453x over previous
//
#include <hip/hip_runtime.h>

typedef unsigned int uint32;
typedef unsigned short ushort16;
typedef __attribute__((ext_vector_type(16))) float f32x16;
typedef __attribute__((ext_vector_type(8)))  short short8;

#define THREADS 256
#define QB 128      // queries per block (4 waves x 32, FR=1)
#define CH 8        // 32-point tiles per LDS chunk (8 KB/buf, 16 KB dbuf)
#define JS 8        // j-slices -> 128x8x2 = 2048 blocks = 8/CU
#define RB 128      // reduce stage-1 blocks

#define GLOAD_LDS(gp, lp) \
    __builtin_amdgcn_global_load_lds( \
        (const __attribute__((address_space(1))) unsigned int*)(gp), \
        (__attribute__((address_space(3))) unsigned int*)(lp), 16, 0, 0)

__device__ inline ushort16 bf16rn(float x) {
    uint32 u = __float_as_uint(x);
    u += 0x7FFFu + ((u >> 16) & 1u);
    return (ushort16)(u >> 16);
}
__device__ inline float bf2f(ushort16 h) { return __uint_as_float(((uint32)h) << 16); }

// K=16 slot map (verified R11-R22). Query side: per coord [h,h,m,m];
// slots 12..14 = 1. Scan side: per coord [bh,bm,bh,bm] of b=-2c; slots
// 12..14 = 3-level split of |b|^2. C-operand carries |a|^2 =>
// D = |a|^2 + |b|^2 - 2 a.b. Padded scan points: s12 = 1e30 sentinel.
__global__ __launch_bounds__(THREADS) void cd_prep(
    const float* __restrict__ A, int n, int padN,
    const float* __restrict__ B, int m, int padM,
    short8* QfA, short8* SfA, float* a2A,
    short8* QfB, short8* SfB, float* a2B,
    uint32* bits)
{
    const int i = blockIdx.x * THREADS + threadIdx.x;
    if (i < n + m) bits[i] = 0x7F800000u;  // +inf

    if (i < padN) {
        ushort16 qs[16], ss[16];
#pragma unroll
        for (int s = 0; s < 16; ++s) { qs[s] = 0; ss[s] = 0; }
        float w = 1e30f;
        if (i < n) {
            float c[3] = {A[3*i], A[3*i+1], A[3*i+2]};
            w = fmaf(c[0], c[0], fmaf(c[1], c[1], c[2]*c[2]));
#pragma unroll
            for (int cc = 0; cc < 3; ++cc) {
                ushort16 h = bf16rn(c[cc]);
                ushort16 md = bf16rn(c[cc] - bf2f(h));
                float bv = -2.f * c[cc];
                ushort16 bh = bf16rn(bv);
                ushort16 bm = bf16rn(bv - bf2f(bh));
                const int b = 4*cc;
                qs[b]=h;  qs[b+1]=h;  qs[b+2]=md; qs[b+3]=md;
                ss[b]=bh; ss[b+1]=bm; ss[b+2]=bh; ss[b+3]=bm;
            }
            qs[12]=0x3F80; qs[13]=0x3F80; qs[14]=0x3F80;
            ushort16 wh = bf16rn(w);
            float r1 = w - bf2f(wh);
            ushort16 wm = bf16rn(r1);
            ss[12]=wh; ss[13]=wm; ss[14]=bf16rn(r1 - bf2f(wm));
        } else {
            ss[12] = bf16rn(1e30f);
        }
        a2A[i] = w;
        const int row = i & 31, grp = i >> 5;
#pragma unroll
        for (int h = 0; h < 2; ++h) {
            short8 qv, sv;
#pragma unroll
            for (int e = 0; e < 8; ++e) { qv[e] = (short)qs[8*h+e]; sv[e] = (short)ss[8*h+e]; }
            QfA[(size_t)grp*64 + h*32 + row] = qv;
            SfA[(size_t)grp*64 + h*32 + row] = sv;
        }
    }
    if (i < padM) {
        ushort16 qs[16], ss[16];
#pragma unroll
        for (int s = 0; s < 16; ++s) { qs[s] = 0; ss[s] = 0; }
        float w = 1e30f;
        if (i < m) {
            float c[3] = {B[3*i], B[3*i+1], B[3*i+2]};
            w = fmaf(c[0], c[0], fmaf(c[1], c[1], c[2]*c[2]));
#pragma unroll
            for (int cc = 0; cc < 3; ++cc) {
                ushort16 h = bf16rn(c[cc]);
                ushort16 md = bf16rn(c[cc] - bf2f(h));
                float bv = -2.f * c[cc];
                ushort16 bh = bf16rn(bv);
                ushort16 bm = bf16rn(bv - bf2f(bh));
                const int b = 4*cc;
                qs[b]=h;  qs[b+1]=h;  qs[b+2]=md; qs[b+3]=md;
                ss[b]=bh; ss[b+1]=bm; ss[b+2]=bh; ss[b+3]=bm;
            }
            qs[12]=0x3F80; qs[13]=0x3F80; qs[14]=0x3F80;
            ushort16 wh = bf16rn(w);
            float r1 = w - bf2f(wh);
            ushort16 wm = bf16rn(r1);
            ss[12]=wh; ss[13]=wm; ss[14]=bf16rn(r1 - bf2f(wm));
        } else {
            ss[12] = bf16rn(1e30f);
        }
        a2B[i] = w;
        const int row = i & 31, grp = i >> 5;
#pragma unroll
        for (int h = 0; h < 2; ++h) {
            short8 qv, sv;
#pragma unroll
            for (int e = 0; e < 8; ++e) { qv[e] = (short)qs[8*h+e]; sv[e] = (short)ss[8*h+e]; }
            QfB[(size_t)grp*64 + h*32 + row] = qv;
            SfB[(size_t)grp*64 + h*32 + row] = sv;
        }
    }
}

__device__ inline float dppmin(float v, int ctrl) {
    float s;
    switch (ctrl) {
        case 0xB1:  s = __int_as_float(__builtin_amdgcn_mov_dpp(__float_as_int(v), 0xB1,  0xf, 0xf, false)); break; // xor1
        case 0x4E:  s = __int_as_float(__builtin_amdgcn_mov_dpp(__float_as_int(v), 0x4E,  0xf, 0xf, false)); break; // xor2
        case 0x141: s = __int_as_float(__builtin_amdgcn_mov_dpp(__float_as_int(v), 0x141, 0xf, 0xf, false)); break; // half_mirror
        default:    s = __int_as_float(__builtin_amdgcn_mov_dpp(__float_as_int(v), 0x140, 0xf, 0xf, false)); break; // row_mirror
    }
    return fminf(v, s);
}

// R15 structure (best known, 40.0 us) with global_load_lds staging:
// the DMA writes LDS directly (wave-uniform base + lane*16 = exactly our
// linear layout) -> no ds_write instructions, no staging registers, 2-inst
// prefetch issue. FR=1, a^2-in-C (D = full sq-dist), 2-tile groups (c0/c1
// ILP), DPP butterfly row-min, atomicMin on float bits (>=0 => exact,
// order-independent). No launch_bounds minimum (R19/20/22: forcing pins
// VGPR below the live set and spills/AGPR-shuffles).
// C layout (m74/m101): col=lane&31, row=(reg&3)+8*(reg>>2)+4*(lane>>5).
__global__ __launch_bounds__(THREADS) void cd_mfma(
    const short8* __restrict__ QfA, const short8* __restrict__ SfA,
    const float* __restrict__ a2A, int padN, int n,
    const short8* __restrict__ QfB, const short8* __restrict__ SfB,
    const float* __restrict__ a2B, int padM, int m,
    uint32* __restrict__ bits)
{
    __shared__ short8 sb[2][CH*64];

    const short8* Qf; const short8* Sf; const float* a2; uint32* outb;
    int nq, padQ, padS;
    if (blockIdx.z == 0) { Qf=QfA; a2=a2A; nq=n; padQ=padN; Sf=SfB; padS=padM; outb=bits;   }
    else                 { Qf=QfB; a2=a2B; nq=m; padQ=padM; Sf=SfA; padS=padN; outb=bits+n; }

    if ((int)(blockIdx.x * QB) >= padQ) return;
    const int ntiles = padS >> 5;
    const int tps = ((ntiles + JS*CH - 1) / (JS*CH)) * CH;
    const int t0 = blockIdx.y * tps;
    const int t1 = min(t0 + tps, ntiles);
    if (t0 >= t1) return;

    const int tid = threadIdx.x, lane = tid & 63, wid = tid >> 6;
    const int qbase = blockIdx.x * QB + wid * 32;

    const short8 av = Qf[(size_t)(qbase >> 5) * 64 + lane];

    // C = a^2 broadcast along rows
    f32x16 pc;
    {
        const int rb = qbase + 4 * (lane >> 5);
#pragma unroll
        for (int r = 0; r < 16; ++r) pc[r] = a2[rb + (r & 3) + 8 * (r >> 2)];
    }

    float rmin[16];
#pragma unroll
    for (int r = 0; r < 16; ++r) rmin[r] = 1e30f;

    const int nch = (t1 - t0 + CH - 1) / CH;

    // staging via global_load_lds: element idx = k*256 + wid*64 + lane;
    // LDS base (wave-uniform) = &sb[buf][k*256 + wid*64]; HW adds lane*16.
    auto stage = [&](int buf, int tb) {
        const int elems = min(CH, t1 - tb) * 64;
        const size_t gb = (size_t)tb * 64;
#pragma unroll
        for (int k = 0; k < 2; ++k) {
            const int idx = k * 256 + wid * 64 + lane;
            if (idx < elems)
                GLOAD_LDS(Sf + gb + idx, &sb[buf][k * 256 + wid * 64]);
        }
    };

    stage(0, t0);
    __syncthreads();   // drains vmcnt -> chunk 0 resident

    int cur = 0;
    for (int ch = 0; ch < nch; ++ch) {
        if (ch + 1 < nch) stage(cur ^ 1, t0 + (ch + 1) * CH);  // issue EARLY

        const int cnt = min(CH, t1 - (t0 + ch * CH));
        int t = 0;
        for (; t + 2 <= cnt; t += 2) {
            const short8 b0 = sb[cur][t*64 + lane];
            const short8 b1 = sb[cur][t*64 + 64 + lane];
            const f32x16 c0 = __builtin_amdgcn_mfma_f32_32x32x16_bf16(av, b0, pc, 0, 0, 0);
            const f32x16 c1 = __builtin_amdgcn_mfma_f32_32x32x16_bf16(av, b1, pc, 0, 0, 0);
#pragma unroll
            for (int r = 0; r < 16; ++r)
                rmin[r] = fminf(fminf(rmin[r], c0[r]), c1[r]);  // v_min3
        }
        if (t < cnt) {
            const short8 b0 = sb[cur][t*64 + lane];
            const f32x16 c0 = __builtin_amdgcn_mfma_f32_32x32x16_bf16(av, b0, pc, 0, 0, 0);
#pragma unroll
            for (int r = 0; r < 16; ++r) rmin[r] = fminf(rmin[r], c0[r]);
        }

        __syncthreads();   // drains DMA (vmcnt) + LDS reads -> swap safe
        cur ^= 1;
    }

    // row-min over the 32 columns: 4 DPP steps + one xor16 shuffle
#pragma unroll
    for (int r = 0; r < 16; ++r) {
        float v = rmin[r];
        v = dppmin(v, 0xB1);
        v = dppmin(v, 0x4E);
        v = dppmin(v, 0x141);
        v = dppmin(v, 0x140);
        v = fminf(v, __shfl_xor(v, 16, 64));
        rmin[r] = v;
    }

    if ((lane & 31) == 0) {
        const int rb = qbase + 4 * (lane >> 5);
#pragma unroll
        for (int r = 0; r < 16; ++r) {
            const int qi = rb + (r & 3) + 8 * (r >> 2);
            if (qi < nq)
                atomicMin(&outb[qi], __float_as_uint(fmaxf(rmin[r], 0.f)));
        }
    }
}

__global__ __launch_bounds__(THREADS) void cd_reduce1(
    const uint32* __restrict__ bits, int count, double* __restrict__ partials)
{
    double s = 0.0;
    for (int i = blockIdx.x * THREADS + threadIdx.x; i < count; i += gridDim.x * THREADS)
        s += (double)sqrtf(__uint_as_float(bits[i]));
#pragma unroll
    for (int off = 32; off; off >>= 1) s += __shfl_down(s, off, 64);
    __shared__ double sw[4];
    const int lane = threadIdx.x & 63, wid = threadIdx.x >> 6;
    if (lane == 0) sw[wid] = s;
    __syncthreads();
    if (threadIdx.x == 0) partials[blockIdx.x] = sw[0] + sw[1] + sw[2] + sw[3];
}

__global__ __launch_bounds__(THREADS) void cd_reduce2(
    const double* __restrict__ partials, int nb, int total, float* __restrict__ out)
{
    double s = 0.0;
    for (int i = threadIdx.x; i < nb; i += THREADS) s += partials[i];
#pragma unroll
    for (int off = 32; off; off >>= 1) s += __shfl_down(s, off, 64);
    __shared__ double sw[4];
    const int lane = threadIdx.x & 63, wid = threadIdx.x >> 6;
    if (lane == 0) sw[wid] = s;
    __syncthreads();
    if (threadIdx.x == 0)
        out[0] = (float)((sw[0] + sw[1] + sw[2] + sw[3]) / (double)total);
}

extern "C" void kernel_launch(void* const* d_in, const int* in_sizes, int n_in,
                              void* d_out, int out_size, void* d_ws, size_t ws_size,
                              hipStream_t stream) {
    const float* a = (const float*)d_in[0];
    const float* b = (const float*)d_in[1];
    const int n = in_sizes[0] / 3;
    const int m = in_sizes[1] / 3;
    const int total = n + m;
    float* out = (float*)d_out;

    const int padN = (n + QB - 1) / QB * QB;
    const int padM = (m + QB - 1) / QB * QB;

    // ws: QfA | SfA | a2A | QfB | SfB | a2B | bits | partials
    char* wp = (char*)d_ws;
    short8* QfA = (short8*)wp;   wp += (size_t)padN * 32;
    short8* SfA = (short8*)wp;   wp += (size_t)padN * 32;
    float*  a2A = (float*)wp;    wp += (size_t)padN * 4;
    short8* QfB = (short8*)wp;   wp += (size_t)padM * 32;
    short8* SfB = (short8*)wp;   wp += (size_t)padM * 32;
    float*  a2B = (float*)wp;    wp += (size_t)padM * 4;
    uint32* bits = (uint32*)wp;  wp += (size_t)total * 4;
    wp = (char*)(((size_t)wp + 255) & ~(size_t)255);
    double* partials = (double*)wp;

    const int prepElems = max(max(padN, padM), total);
    cd_prep<<<(prepElems + THREADS - 1) / THREADS, THREADS, 0, stream>>>(
        a, n, padN, b, m, padM, QfA, SfA, a2A, QfB, SfB, a2B, bits);

    const int gx = max(padN, padM) / QB;
    dim3 grid(gx, JS, 2);
    cd_mfma<<<grid, THREADS, 0, stream>>>(QfA, SfA, a2A, padN, n,
                                          QfB, SfB, a2B, padM, m, bits);

    cd_reduce1<<<RB, THREADS, 0, stream>>>(bits, total, partials);
    cd_reduce2<<<1, THREADS, 0, stream>>>(partials, RB, total, out);
}